// Round 8
// baseline (122.854 us; speedup 1.0000x reference)
//
#include <hip/hip_runtime.h>

// B=8, T=2048, C=768, HS=64. fp32 in/out; bf16 MFMA internally.

typedef short bf16x8 __attribute__((ext_vector_type(8)));  // 8 bf16 = 4 VGPR
typedef short bf16x4 __attribute__((ext_vector_type(4)));  // 4 bf16 = 2 VGPR
typedef float f32x4  __attribute__((ext_vector_type(4)));
typedef unsigned u32x2 __attribute__((ext_vector_type(2)));

#define MFMA_BF16(a, b, c) __builtin_amdgcn_mfma_f32_16x16x32_bf16((a), (b), (c), 0, 0, 0)

#if __has_builtin(__builtin_amdgcn_mfma_f32_16x16x16bf16_1k)
#define HAVE_MFMA16 1
#define MFMA16(a, b, c) __builtin_amdgcn_mfma_f32_16x16x16bf16_1k((a), (b), (c), 0, 0, 0)
#else
#define HAVE_MFMA16 0
#endif

// scale = C^-0.5 * log2(e), folded into Wq at prep time
#define SCALE_LOG2E 0.05206626f

__device__ __forceinline__ unsigned rbf(float f) {  // RNE bf16 in high 16 bits
  unsigned u = __builtin_bit_cast(unsigned, f);
  return u + 0x7fffu + ((u >> 16) & 1u);
}
__device__ __forceinline__ short f2bf(float f) { return (short)(rbf(f) >> 16); }
__device__ __forceinline__ unsigned pkbf(float a, float b) {  // [lo=a, hi=b]
  return (rbf(a) >> 16) | (rbf(b) & 0xFFFF0000u);
}
__device__ __forceinline__ float bsum(unsigned dw) {  // sum of 2 packed bf16
  float lo = __builtin_bit_cast(float, dw << 16);
  float hi = __builtin_bit_cast(float, dw & 0xFFFF0000u);
  return lo + hi;
}

__device__ __forceinline__ void load_lds16(const void* g, void* l) {
  __builtin_amdgcn_global_load_lds(
      (const __attribute__((address_space(1))) void*)g,
      (__attribute__((address_space(3))) void*)l, 16, 0, 0);
}

// ---------------------------------------------------------------------------
// Kernel 1: W (x3, [768][64] fp32) -> wtf in B-FRAGMENT order:
//   wtf[ks 0..23][nt 0..11][lane 0..63][8 bf16]
// nt 0-3 = Wq (PRE-SCALED by C^-0.5*log2e), 4-7 = Wk, 8-11 = Wv.
// ---------------------------------------------------------------------------
__global__ void prep_wt(const float* __restrict__ Wk, const float* __restrict__ Wq,
                        const float* __restrict__ Wv, short* __restrict__ wtf) {
  int gid = blockIdx.x * blockDim.x + threadIdx.x;
  if (gid >= 24 * 12 * 64) return;
  int ks   = gid / 768;
  int rem  = gid - ks * 768;
  int nt   = rem >> 6;
  int lane = rem & 63;
  int quad = lane >> 4, col = lane & 15;
  const float* W = (nt < 4) ? Wq : (nt < 8) ? Wk : Wv;
  float s = (nt < 4) ? SCALE_LOG2E : 1.0f;
  int h  = (nt & 3) * 16 + col;
  int k0 = ks * 32 + quad * 8;
  bf16x8 v;
#pragma unroll
  for (int j = 0; j < 8; ++j) v[j] = f2bf(W[(k0 + j) * 64 + h] * s);
  *(bf16x8*)(wtf + (size_t)gid * 8) = v;
}

// ---------------------------------------------------------------------------
// Kernel 2: projections. 512 blocks x 256 thr, dbuf LDS, 1 barrier/k-step.
// R7 epilogue: emit Q/K/V in EXACT attn fragment order so attn's K-loop is
// zero-LDS:
//  - qfb[tq][c][lane][8]: Q B-frag (h-fast) via per-wave LDS transpose
//  - kfb[b][v][t*2+c][lane][8]: K A-frag (h-fast) via per-wave LDS transpose
//  - vfb[b][v][t*2+pg][lane][8]: V MFMA16 A-frags -- proj's C-layout already
//    IS this layout per lane (keys quad*4+rr at h=col): pack only, no LDS.
// Transposes reuse wb[0] (dead after the final loop barrier), same-wave RAW
// only (no extra __syncthreads).
// ---------------------------------------------------------------------------
__global__ __launch_bounds__(256) void proj_kernel(
    const float* __restrict__ x, const short* __restrict__ wtf,
    short* __restrict__ qfb, short* __restrict__ kfb, short* __restrict__ vfb) {
  __shared__ __attribute__((aligned(16))) short xa[2][32][40];  // A tile bf16
  __shared__ __attribute__((aligned(16))) short wb[2][6144];    // 12 KB B frags

  const int tid  = threadIdx.x;
  const int wave = tid >> 6;
  const int lane = tid & 63;
  const int quad = lane >> 4;
  const int col  = lane & 15;
  const int msub = wave >> 1;
  const int nh   = wave & 1;
  const int m0   = blockIdx.x * 32;

  const int srow = tid >> 3, sc4 = tid & 7;
  const float* xsrc = x + (size_t)(m0 + srow) * 768 + sc4 * 4;

  auto dma_wt = [&](int ks, int buf) {
    const short* wsrc = wtf + (size_t)ks * 6144;
#pragma unroll
    for (int i = 0; i < 3; ++i) {
      int seg = wave * 3 + i;
      load_lds16(wsrc + seg * 512 + lane * 8, &wb[buf][seg * 512]);
    }
  };
  auto write_xa = [&](int buf, const float4& xv) {
    unsigned lo = pkbf(xv.x, xv.y);
    unsigned hi = pkbf(xv.z, xv.w);
    *(uint2*)&xa[buf][srow][sc4 * 4] = make_uint2(lo, hi);
  };

  f32x4 acc[6];
#pragma unroll
  for (int i = 0; i < 6; ++i) acc[i] = (f32x4){0.f, 0.f, 0.f, 0.f};

  float4 xv = *(const float4*)xsrc;
  dma_wt(0, 0);
  write_xa(0, xv);
  xv = *(const float4*)(xsrc + 32);

  for (int ks = 0; ks < 24; ++ks) {
    const int cur = ks & 1;
    __syncthreads();  // drains DMA(ks) [vmcnt] + xa writes [lgkm]

    if (ks + 1 < 24) {
      dma_wt(ks + 1, cur ^ 1);
      write_xa(cur ^ 1, xv);
      if (ks + 2 < 24) xv = *(const float4*)(xsrc + (ks + 2) * 32);
    }

    bf16x8 af = *(const bf16x8*)&xa[cur][msub * 16 + col][quad * 8];
#pragma unroll
    for (int i = 0; i < 6; ++i) {
      bf16x8 bfr = *(const bf16x8*)&wb[cur][((nh * 6 + i) * 64 + lane) * 8];
      acc[i] = MFMA_BF16(af, bfr, acc[i]);
    }
  }

  // ---- epilogue. acc C/D layout: col = lane&15 (h), row = quad*4+rr (tok) --
  const int b  = m0 >> 11;
  const int tq = (m0 >> 4) + msub;     // global 16-token tile (0..1023)
  const int v  = (m0 & 2047) >> 5;     // 32-key visit within batch
  // wb[0] is free after the final barrier (last k-step reads wb[1]).
  // Transpose zones (shorts): [16 rows][40] each, 16B-aligned rows.
  short* zbase = &wb[0][0];

  if (nh == 0) {
    // nt 0..3 = Q h0-63 (acc[0..3]); nt 4,5 = K h0-31 (acc[4],acc[5])
    short* qz = zbase + msub * 1920;   // 2 chunks x [16 q][40]
    short* kz = qz + 1280;             // [16 key][40]
#pragma unroll
    for (int i = 0; i < 2; ++i)
#pragma unroll
      for (int rr = 0; rr < 4; ++rr) {
        int row = quad * 4 + rr;
        qz[row * 40 + i * 16 + col]       = f2bf(acc[i][rr]);      // c=0
        qz[640 + row * 40 + i * 16 + col] = f2bf(acc[2 + i][rr]);  // c=1
        kz[row * 40 + i * 16 + col]       = f2bf(acc[4 + i][rr]);  // K c=0
      }
    // same-wave RAW -> compiler lgkmcnt; read frags + coalesced stores
#pragma unroll
    for (int c = 0; c < 2; ++c) {
      bf16x8 fq = *(const bf16x8*)&qz[c * 640 + col * 40 + quad * 8];
      *(bf16x8*)(qfb + ((size_t)(tq * 2 + c)) * 512 + lane * 8) = fq;
    }
    bf16x8 fk = *(const bf16x8*)&kz[col * 40 + quad * 8];
    *(bf16x8*)(kfb + ((size_t)((b * 64 + v) * 4 + msub * 2 + 0)) * 512 + lane * 8) = fk;
  } else {
    // nt 6,7 = K h32-63 (acc[0],acc[1]); nt 8..11 = V h0-63 (acc[2..5])
    short* kz = zbase + 3840 + msub * 640;  // [16 key][40]
#pragma unroll
    for (int i = 0; i < 2; ++i)
#pragma unroll
      for (int rr = 0; rr < 4; ++rr)
        kz[(quad * 4 + rr) * 40 + i * 16 + col] = f2bf(acc[i][rr]);
    bf16x8 fk = *(const bf16x8*)&kz[col * 40 + quad * 8];
    *(bf16x8*)(kfb + ((size_t)((b * 64 + v) * 4 + msub * 2 + 1)) * 512 + lane * 8) = fk;

    // V: acc IS the MFMA16 A-frag layout per lane -- pack & store, no LDS.
    // vfb lane 16B = [ht=2pg frag (4 bf16) | ht=2pg+1 frag (4 bf16)]
#pragma unroll
    for (int pg = 0; pg < 2; ++pg) {
      unsigned w0 = pkbf(acc[2 + 2 * pg][0], acc[2 + 2 * pg][1]);
      unsigned w1 = pkbf(acc[2 + 2 * pg][2], acc[2 + 2 * pg][3]);
      unsigned w2 = pkbf(acc[3 + 2 * pg][0], acc[3 + 2 * pg][1]);
      unsigned w3 = pkbf(acc[3 + 2 * pg][2], acc[3 + 2 * pg][3]);
      uint4 pu = make_uint4(w0, w1, w2, w3);
      *(uint4*)(vfb + ((size_t)((b * 64 + v) * 4 + msub * 2 + pg)) * 512 + lane * 8) = pu;
    }
  }
}

// ---------------------------------------------------------------------------
// Kernel 3: flash attention, ZERO-LDS K-loop (R7). 512 x 256.
// Per visit: 8 contiguous b128 global loads (kfb/vfb frag-order, L2-hot) +
// 8 S^T MFMA + no-max softmax + 16 MFMA16 PV (P straight from S^T C-regs).
// No LDS, no barriers in the loop; dbuf register prefetch; 4-way split-K
// across waves (visits w, w+4, ...), pure-add fp32 combine at the end.
// ---------------------------------------------------------------------------
__global__ __launch_bounds__(256) void attn_kernel(
    const short* __restrict__ qfb, const short* __restrict__ kfb,
    const short* __restrict__ vfb, float* __restrict__ out) {
  __shared__ float comb[3 * 64 * 36];  // split-K combine buffer (27.6 KB)

  const int tid  = threadIdx.x;
  const int wave = tid >> 6;
  const int lane = tid & 63;
  const int quad = lane >> 4;
  const int col  = lane & 15;

  const int bx = blockIdx.x;
  const int b  = bx & 7;
  const int qt = 63 - (bx >> 3);            // heavy blocks launch first
  const size_t qbase = (size_t)b * 2048 + qt * 32;

  // Q B-frags from qfb (contiguous): qf[qs][c]
  bf16x8 qf[2][2];
#pragma unroll
  for (int qs = 0; qs < 2; ++qs)
#pragma unroll
    for (int c = 0; c < 2; ++c)
      qf[qs][c] = *(const bf16x8*)(
          qfb + ((size_t)((b * 128 + qt * 2 + qs) * 2 + c)) * 512 + lane * 8);

  f32x4 o[2][4];  // O^T accumulators: [qs][ht], row=h_local, col=q
#pragma unroll
  for (int qs = 0; qs < 2; ++qs)
#pragma unroll
    for (int ht = 0; ht < 4; ++ht) o[qs][ht] = (f32x4){0.f, 0.f, 0.f, 0.f};
  float osum[2] = {0.f, 0.f};

  const int nv = qt + 1;  // 32-key visits; wave w takes w, w+4, ...
  const int mycount = (nv > wave) ? ((nv - wave + 3) >> 2) : 0;

  bf16x8 kf0[4], vv0[4], kf1[4], vv1[4];
  auto issue = [&](int v, bf16x8* kf, bf16x8* vv) {
    const short* kp = kfb + ((size_t)(b * 64 + v) * 4) * 512;
    const short* vp = vfb + ((size_t)(b * 64 + v) * 4) * 512;
#pragma unroll
    for (int g = 0; g < 4; ++g) {
      kf[g] = *(const bf16x8*)(kp + g * 512 + lane * 8);  // 1 KB contiguous
      vv[g] = *(const bf16x8*)(vp + g * 512 + lane * 8);
    }
  };

  auto body = [&](int v, const bf16x8* kf, const bf16x8* vv) {
    // ---- S^T = K Q^T : all operands in registers ----
    f32x4 st[2][2];  // [qs][t]
#pragma unroll
    for (int qs = 0; qs < 2; ++qs)
#pragma unroll
      for (int t = 0; t < 2; ++t) st[qs][t] = (f32x4){0.f, 0.f, 0.f, 0.f};
#pragma unroll
    for (int t = 0; t < 2; ++t)
#pragma unroll
      for (int qs = 0; qs < 2; ++qs) {
        st[qs][t] = MFMA_BF16(kf[t * 2 + 0], qf[qs][0], st[qs][t]);
        st[qs][t] = MFMA_BF16(kf[t * 2 + 1], qf[qs][1], st[qs][t]);
      }

    // ---- p = exp2(s) (scale pre-folded); causal mask on diagonal visit ----
    const bool diag = (v == qt);  // wave-uniform
    unsigned d[2][2][2];          // packed bf16 P: [qs][t][pair]
#pragma unroll
    for (int qs = 0; qs < 2; ++qs) {
      float part = 0.f;
#pragma unroll
      for (int t = 0; t < 2; ++t) {
        float pr[4];
#pragma unroll
        for (int rr = 0; rr < 4; ++rr) {
          float sv = st[qs][t][rr];
          if (diag && (t * 16 + quad * 4 + rr) > (qs * 16 + col)) sv = -1e30f;
          pr[rr] = __builtin_amdgcn_exp2f(sv);
        }
        d[qs][t][0] = pkbf(pr[0], pr[1]);
        d[qs][t][1] = pkbf(pr[2], pr[3]);
        part += bsum(d[qs][t][0]) + bsum(d[qs][t][1]);
      }
      part += __shfl_xor(part, 16);
      part += __shfl_xor(part, 32);
      osum[qs] += part;
    }

#if HAVE_MFMA16
    // ---- O^T += V^T P^T : V frags straight from vv regs, P from d regs ----
#pragma unroll
    for (int t = 0; t < 2; ++t)
#pragma unroll
      for (int pg = 0; pg < 2; ++pg) {
        uint4 u = __builtin_bit_cast(uint4, vv[t * 2 + pg]);
        u32x2 l2 = {u.x, u.y}, h2 = {u.z, u.w};
        bf16x4 vlo = __builtin_bit_cast(bf16x4, l2);  // ht = 2*pg
        bf16x4 vhi = __builtin_bit_cast(bf16x4, h2);  // ht = 2*pg+1
#pragma unroll
        for (int qs = 0; qs < 2; ++qs) {
          u32x2 pd = {d[qs][t][0], d[qs][t][1]};
          bf16x4 pb = __builtin_bit_cast(bf16x4, pd);
          o[qs][2 * pg]     = MFMA16(vlo, pb, o[qs][2 * pg]);
          o[qs][2 * pg + 1] = MFMA16(vhi, pb, o[qs][2 * pg + 1]);
        }
      }
#else
    // ---- fallback: shfl-transpose P (K=32) + shfl-gather V bf16x8 ----
    bf16x8 pbf[2];
#pragma unroll
    for (int qs = 0; qs < 2; ++qs) {
      unsigned dA0 = d[qs][0][0], dB0 = d[qs][0][1];
      unsigned dA1 = d[qs][1][0], dB1 = d[qs][1][1];
      int base = ((quad & 1) << 5) + col;
      unsigned a0  = __shfl(dA0, base),      a1  = __shfl(dA1, base);
      unsigned b0  = __shfl(dB0, base),      b1  = __shfl(dB1, base);
      unsigned a0h = __shfl(dA0, base + 16), a1h = __shfl(dA1, base + 16);
      unsigned b0h = __shfl(dB0, base + 16), b1h = __shfl(dB1, base + 16);
      bool hi = quad >= 2;
      uint4 pu = make_uint4(hi ? a1 : a0, hi ? b1 : b0,
                            hi ? a1h : a0h, hi ? b1h : b0h);
      pbf[qs] = __builtin_bit_cast(bf16x8, pu);
    }
#pragma unroll
    for (int ht = 0; ht < 4; ++ht) {
      int pg = ht >> 1;
      bool odd = ht & 1;
      int L0 = ((quad & 1) * 2) * 16 + col, L1 = L0 + 16;
      uint4 u0 = __builtin_bit_cast(uint4, vv[pg]);
      uint4 u1 = __builtin_bit_cast(uint4, vv[2 + pg]);
      unsigned s0 = odd ? u0.z : u0.x, s1 = odd ? u0.w : u0.y;
      unsigned s2 = odd ? u1.z : u1.x, s3 = odd ? u1.w : u1.y;
      unsigned d0a = __shfl(s0, L0), d1a = __shfl(s1, L0);
      unsigned d2a = __shfl(s0, L1), d3a = __shfl(s1, L1);
      unsigned d0b = __shfl(s2, L0), d1b = __shfl(s3, L0);
      unsigned d2b = __shfl(s2, L1), d3b = __shfl(s3, L1);
      bool t1 = quad >= 2;
      uint4 vu = make_uint4(t1 ? d0b : d0a, t1 ? d1b : d1a,
                            t1 ? d2b : d2a, t1 ? d3b : d3a);
      bf16x8 vf8 = __builtin_bit_cast(bf16x8, vu);
#pragma unroll
      for (int qs = 0; qs < 2; ++qs)
        o[qs][ht] = MFMA_BF16(vf8, pbf[qs], o[qs][ht]);
    }
#endif
  };

  // ---- barrier-free K-loop with ping-pong register double-buffer ----
  if (mycount > 0) issue(wave, kf0, vv0);
  {
    int i = 0, v = wave;
    while (i < mycount) {
      if (i + 1 < mycount) issue(v + 4, kf1, vv1);
      body(v, kf0, vv0);
      ++i; v += 4;
      if (i >= mycount) break;
      if (i + 1 < mycount) issue(v + 4, kf0, vv0);
      body(v, kf1, vv1);
      ++i; v += 4;
    }
  }

  // ---- 4-way split-K combine (pure fp32 add; no-max softmax) ----
  __syncthreads();
  if (wave > 0) {
    float* p = comb + ((wave - 1) * 64 + lane) * 36;
#pragma unroll
    for (int qs = 0; qs < 2; ++qs)
#pragma unroll
      for (int ht = 0; ht < 4; ++ht)
        *(f32x4*)(p + (qs * 4 + ht) * 4) = o[qs][ht];
    p[32] = osum[0];
    p[33] = osum[1];
  }
  __syncthreads();
  if (wave == 0) {
#pragma unroll
    for (int w = 1; w < 4; ++w) {
      const float* p = comb + ((w - 1) * 64 + lane) * 36;
#pragma unroll
      for (int qs = 0; qs < 2; ++qs)
#pragma unroll
        for (int ht = 0; ht < 4; ++ht)
          o[qs][ht] += *(const f32x4*)(p + (qs * 4 + ht) * 4);
      osum[0] += p[32];
      osum[1] += p[33];
    }
    // ---- epilogue: O^T C-layout -> packed float4 stores ----
#pragma unroll
    for (int qs = 0; qs < 2; ++qs) {
      float inv = 1.0f / osum[qs];
#pragma unroll
      for (int ht = 0; ht < 4; ++ht) {
        f32x4 val = o[qs][ht];
#pragma unroll
        for (int rr = 0; rr < 4; ++rr) val[rr] *= inv;
        *(f32x4*)(out + (qbase + qs * 16 + col) * 64 + ht * 16 + quad * 4) = val;
      }
    }
  }
}

// ---------------------------------------------------------------------------
extern "C" void kernel_launch(void* const* d_in, const int* in_sizes, int n_in,
                              void* d_out, int out_size, void* d_ws, size_t ws_size,
                              hipStream_t stream) {
  const float* x  = (const float*)d_in[0];
  const float* Wk = (const float*)d_in[1];
  const float* Wq = (const float*)d_in[2];
  const float* Wv = (const float*)d_in[3];
  float* out = (float*)d_out;

  char* ws = (char*)d_ws;
  // ws layout: wtf (294912 B) | qfb 2MB | kfb 2MB | vfb 2MB
  short* wtf = (short*)(ws);
  short* qfb = (short*)(ws + (512 << 10));
  short* kfb = (short*)(ws + (512 << 10) + (2 << 20));
  short* vfb = (short*)(ws + (512 << 10) + (4 << 20));

  prep_wt<<<72, 256, 0, stream>>>(Wk, Wq, Wv, wtf);
  proj_kernel<<<512, 256, 0, stream>>>(x, wtf, qfb, kfb, vfb);
  attn_kernel<<<512, 256, 0, stream>>>(qfb, kfb, vfb, out);
}

// Round 9
// 116.755 us; speedup vs baseline: 1.0522x; 1.0522x over previous
//
#include <hip/hip_runtime.h>

// B=8, T=2048, C=768, HS=64. fp32 in/out; bf16 MFMA internally.

typedef short bf16x8 __attribute__((ext_vector_type(8)));  // 8 bf16 = 4 VGPR
typedef short bf16x4 __attribute__((ext_vector_type(4)));  // 4 bf16 = 2 VGPR
typedef float f32x4  __attribute__((ext_vector_type(4)));
typedef unsigned u32x2 __attribute__((ext_vector_type(2)));

#define MFMA_BF16(a, b, c) __builtin_amdgcn_mfma_f32_16x16x32_bf16((a), (b), (c), 0, 0, 0)

#if __has_builtin(__builtin_amdgcn_mfma_f32_16x16x16bf16_1k)
#define HAVE_MFMA16 1
#define MFMA16(a, b, c) __builtin_amdgcn_mfma_f32_16x16x16bf16_1k((a), (b), (c), 0, 0, 0)
#else
#define HAVE_MFMA16 0
#endif

// scale = C^-0.5 * log2(e), folded into Wq at prep time
#define SCALE_LOG2E 0.05206626f

__device__ __forceinline__ unsigned rbf(float f) {  // RNE bf16 in high 16 bits
  unsigned u = __builtin_bit_cast(unsigned, f);
  return u + 0x7fffu + ((u >> 16) & 1u);
}
__device__ __forceinline__ short f2bf(float f) { return (short)(rbf(f) >> 16); }
__device__ __forceinline__ unsigned pkbf(float a, float b) {  // [lo=a, hi=b]
  return (rbf(a) >> 16) | (rbf(b) & 0xFFFF0000u);
}
__device__ __forceinline__ float bsum(unsigned dw) {  // sum of 2 packed bf16
  float lo = __builtin_bit_cast(float, dw << 16);
  float hi = __builtin_bit_cast(float, dw & 0xFFFF0000u);
  return lo + hi;
}

__device__ __forceinline__ void load_lds16(const void* g, void* l) {
  __builtin_amdgcn_global_load_lds(
      (const __attribute__((address_space(1))) void*)g,
      (__attribute__((address_space(3))) void*)l, 16, 0, 0);
}

// ---------------------------------------------------------------------------
// Kernel 1: W (x3, [768][64] fp32) -> wtf in B-FRAGMENT order:
//   wtf[ks 0..23][nt 0..11][lane 0..63][8 bf16]
// nt 0-3 = Wq (PRE-SCALED by C^-0.5*log2e), 4-7 = Wk, 8-11 = Wv.
// ---------------------------------------------------------------------------
__global__ void prep_wt(const float* __restrict__ Wk, const float* __restrict__ Wq,
                        const float* __restrict__ Wv, short* __restrict__ wtf) {
  int gid = blockIdx.x * blockDim.x + threadIdx.x;
  if (gid >= 24 * 12 * 64) return;
  int ks   = gid / 768;
  int rem  = gid - ks * 768;
  int nt   = rem >> 6;
  int lane = rem & 63;
  int quad = lane >> 4, col = lane & 15;
  const float* W = (nt < 4) ? Wq : (nt < 8) ? Wk : Wv;
  float s = (nt < 4) ? SCALE_LOG2E : 1.0f;
  int h  = (nt & 3) * 16 + col;
  int k0 = ks * 32 + quad * 8;
  bf16x8 v;
#pragma unroll
  for (int j = 0; j < 8; ++j) v[j] = f2bf(W[(k0 + j) * 64 + h] * s);
  *(bf16x8*)(wtf + (size_t)gid * 8) = v;
}

// ---------------------------------------------------------------------------
// Kernel 2: projections (R6 structure). 512 blocks x 256 thr, dbuf LDS,
// 1 barrier/k-step. Outputs:
//   qb/kb bf16 [b][t][64]  (as R6)
//   vfb    MFMA16-A-frag order [b][v][t*2+pg][lane][8] (R7's free pack --
//          proj's C-layout per lane ALREADY is this layout; no LDS, no
//          transpose, coalesced uint4 stores)
// ---------------------------------------------------------------------------
__global__ __launch_bounds__(256) void proj_kernel(
    const float* __restrict__ x, const short* __restrict__ wtf,
    short* __restrict__ qb, short* __restrict__ kb, short* __restrict__ vfb) {
  __shared__ __attribute__((aligned(16))) short xa[2][32][40];  // A tile bf16
  __shared__ __attribute__((aligned(16))) short wb[2][6144];    // 12 KB B frags

  const int tid  = threadIdx.x;
  const int wave = tid >> 6;
  const int lane = tid & 63;
  const int quad = lane >> 4;
  const int col  = lane & 15;
  const int msub = wave >> 1;
  const int nh   = wave & 1;
  const int m0   = blockIdx.x * 32;

  const int srow = tid >> 3, sc4 = tid & 7;
  const float* xsrc = x + (size_t)(m0 + srow) * 768 + sc4 * 4;

  auto dma_wt = [&](int ks, int buf) {
    const short* wsrc = wtf + (size_t)ks * 6144;
#pragma unroll
    for (int i = 0; i < 3; ++i) {
      int seg = wave * 3 + i;
      load_lds16(wsrc + seg * 512 + lane * 8, &wb[buf][seg * 512]);
    }
  };
  auto write_xa = [&](int buf, const float4& xv) {
    unsigned lo = pkbf(xv.x, xv.y);
    unsigned hi = pkbf(xv.z, xv.w);
    *(uint2*)&xa[buf][srow][sc4 * 4] = make_uint2(lo, hi);
  };

  f32x4 acc[6];
#pragma unroll
  for (int i = 0; i < 6; ++i) acc[i] = (f32x4){0.f, 0.f, 0.f, 0.f};

  float4 xv = *(const float4*)xsrc;
  dma_wt(0, 0);
  write_xa(0, xv);
  xv = *(const float4*)(xsrc + 32);

  for (int ks = 0; ks < 24; ++ks) {
    const int cur = ks & 1;
    __syncthreads();  // drains DMA(ks) [vmcnt] + xa writes [lgkm]

    if (ks + 1 < 24) {
      dma_wt(ks + 1, cur ^ 1);
      write_xa(cur ^ 1, xv);
      if (ks + 2 < 24) xv = *(const float4*)(xsrc + (ks + 2) * 32);
    }

    bf16x8 af = *(const bf16x8*)&xa[cur][msub * 16 + col][quad * 8];
#pragma unroll
    for (int i = 0; i < 6; ++i) {
      bf16x8 bfr = *(const bf16x8*)&wb[cur][((nh * 6 + i) * 64 + lane) * 8];
      acc[i] = MFMA_BF16(af, bfr, acc[i]);
    }
  }

  // ---- epilogue. acc C/D layout: col = lane&15, row = quad*4 + rr ----
  const int b  = m0 >> 11;
  const int mrow  = m0 + msub * 16;
  const int v  = (m0 & 2047) >> 5;     // 32-key visit within batch

#pragma unroll
  for (int i = 0; i < 6; ++i) {
    int nt = nh * 6 + i;
    if (nt < 8) {  // q or k: [b][tok][h]
      short* dst = (nt < 4) ? qb : kb;
      int h = (nt & 3) * 16 + col;
#pragma unroll
      for (int r = 0; r < 4; ++r)
        dst[(size_t)(mrow + quad * 4 + r) * 64 + h] = f2bf(acc[i][r]);
    }
  }
  if (nh == 1) {
    // V (acc[2..5]): pack straight into MFMA16 A-frag order. Lane 16B =
    // [ht=2pg frag (4 bf16) | ht=2pg+1 frag (4 bf16)], key-tile t = msub.
#pragma unroll
    for (int pg = 0; pg < 2; ++pg) {
      unsigned w0 = pkbf(acc[2 + 2 * pg][0], acc[2 + 2 * pg][1]);
      unsigned w1 = pkbf(acc[2 + 2 * pg][2], acc[2 + 2 * pg][3]);
      unsigned w2 = pkbf(acc[3 + 2 * pg][0], acc[3 + 2 * pg][1]);
      unsigned w3 = pkbf(acc[3 + 2 * pg][2], acc[3 + 2 * pg][3]);
      uint4 pu = make_uint4(w0, w1, w2, w3);
      *(uint4*)(vfb + ((size_t)((b * 64 + v) * 4 + msub * 2 + pg)) * 512 + lane * 8) = pu;
    }
  }
}

// ---------------------------------------------------------------------------
// Kernel 3: flash attention (R8). 512 x 256, 4-way split-K across waves
// (visits w, w+4, ...), barrier-free K-loop:
//  - K: contiguous global->reg prefetch + wave-private LDS dbuf (R6; the
//    register-cheap dbuf -- R7's all-register ping-pong blew the 128-VGPR
//    occupancy step)
//  - V: ZERO-LDS -- frag-order vfb loads direct to regs, single-buffered,
//    issued before the K-commit so they hide behind S^T+softmax
//  - S^T = K.Q^T; its C-output IS the MFMA16 B-layout -> PV straight from
//    registers, no P transpose, no P LDS
// Per-visit LDS ops: 8 (was 20 in R6). No-max softmax; pure-add combine.
// ---------------------------------------------------------------------------
__global__ __launch_bounds__(256) void attn_kernel(
    const short* __restrict__ qb, const short* __restrict__ kb,
    const short* __restrict__ vfb, float* __restrict__ out) {
  // K staging: 4 waves x [32 key][72] shorts = 18432 B; combine overlay
  // needs 3*64*36 floats = 27648 B. Size for the max.
  __shared__ __attribute__((aligned(16))) short lds[13824];

  const int tid  = threadIdx.x;
  const int wave = tid >> 6;
  const int lane = tid & 63;
  const int quad = lane >> 4;
  const int col  = lane & 15;

  short* ksw = lds + wave * 2304;  // wave-private K tile [32 key][72]

  const int bx = blockIdx.x;
  const int b  = bx & 7;
  const int qt = 63 - (bx >> 3);            // heavy blocks launch first
  const size_t qbase = (size_t)b * 2048 + qt * 32;

  // Q B-frags (pre-scaled): qf[qs][c] -> Q[q=col][h=c*32+quad*8+j]
  bf16x8 qf[2][2];
#pragma unroll
  for (int qs = 0; qs < 2; ++qs)
#pragma unroll
    for (int c = 0; c < 2; ++c)
      qf[qs][c] = *(const bf16x8*)(qb + (qbase + qs * 16 + col) * 64 + c * 32 + quad * 8);

  f32x4 o[2][4];  // O^T accumulators: [qs][ht], row=h_local, col=q
#pragma unroll
  for (int qs = 0; qs < 2; ++qs)
#pragma unroll
    for (int ht = 0; ht < 4; ++ht) o[qs][ht] = (f32x4){0.f, 0.f, 0.f, 0.f};
  float osum[2] = {0.f, 0.f};

  const int nv = qt + 1;  // 32-key visits; wave w takes w, w+4, ...
  const int mycount = (nv > wave) ? ((nv - wave + 3) >> 2) : 0;

  const short* kB = kb + (size_t)b * 2048 * 64;
  const short* vB = vfb + (size_t)b * 64 * 4 * 512;

  bf16x8 kreg[4], vv[4];
  auto issue_k = [&](int v) {  // contiguous 4 KB
    const short* ksrc = kB + v * 32 * 64;
#pragma unroll
    for (int it = 0; it < 4; ++it)
      kreg[it] = *(const bf16x8*)(ksrc + lane * 8 + it * 512);
  };
  auto issue_v = [&](int v) {  // frag-order, 1 KB contiguous per load
    const short* vp = vB + (size_t)v * 4 * 512;
#pragma unroll
    for (int g = 0; g < 4; ++g)
      vv[g] = *(const bf16x8*)(vp + g * 512 + lane * 8);
  };
  if (mycount > 0) issue_k(wave);

  for (int i = 0; i < mycount; ++i) {
    const int v = wave + i * 4;

    issue_v(v);  // flies through commit + S^T + softmax (~300 cyc)

    // ---- commit prefetched K to private LDS (consumes kreg) ----
#pragma unroll
    for (int it = 0; it < 4; ++it) {
      int e = lane * 8 + it * 512;
      *(bf16x8*)&ksw[(e >> 6) * 72 + (e & 63)] = kreg[it];  // [key][h]
    }
    if (i + 1 < mycount) issue_k(v + 4);  // K prefetch for next visit

    // ---- S^T = K Q^T : A=K[key][h] from LDS, B=Q (regs) ----
    f32x4 st[2][2];  // [qs][t: 16-key tile]
#pragma unroll
    for (int qs = 0; qs < 2; ++qs)
#pragma unroll
      for (int t = 0; t < 2; ++t) st[qs][t] = (f32x4){0.f, 0.f, 0.f, 0.f};
#pragma unroll
    for (int t = 0; t < 2; ++t) {
      const bf16x8 a0 = *(const bf16x8*)&ksw[(t * 16 + col) * 72 + quad * 8];
      const bf16x8 a1 = *(const bf16x8*)&ksw[(t * 16 + col) * 72 + 32 + quad * 8];
#pragma unroll
      for (int qs = 0; qs < 2; ++qs) {
        st[qs][t] = MFMA_BF16(a0, qf[qs][0], st[qs][t]);
        st[qs][t] = MFMA_BF16(a1, qf[qs][1], st[qs][t]);
      }
    }

    // ---- p = exp2(s) (scale pre-folded); causal mask on diagonal visit ----
    const bool diag = (v == qt);  // wave-uniform
    unsigned d[2][2][2];          // packed bf16 P: [qs][t][pair]
#pragma unroll
    for (int qs = 0; qs < 2; ++qs) {
      float part = 0.f;
#pragma unroll
      for (int t = 0; t < 2; ++t) {
        float pr[4];
#pragma unroll
        for (int rr = 0; rr < 4; ++rr) {
          float sv = st[qs][t][rr];
          if (diag && (t * 16 + quad * 4 + rr) > (qs * 16 + col)) sv = -1e30f;
          pr[rr] = __builtin_amdgcn_exp2f(sv);
        }
        d[qs][t][0] = pkbf(pr[0], pr[1]);
        d[qs][t][1] = pkbf(pr[2], pr[3]);
        part += bsum(d[qs][t][0]) + bsum(d[qs][t][1]);
      }
      part += __shfl_xor(part, 16);
      part += __shfl_xor(part, 32);
      osum[qs] += part;
    }

#if HAVE_MFMA16
    // ---- O^T += V^T P^T : V frags straight from vv regs, P from d regs ----
#pragma unroll
    for (int t = 0; t < 2; ++t)
#pragma unroll
      for (int pg = 0; pg < 2; ++pg) {
        uint4 u = __builtin_bit_cast(uint4, vv[t * 2 + pg]);
        u32x2 l2 = {u.x, u.y}, h2 = {u.z, u.w};
        bf16x4 vlo = __builtin_bit_cast(bf16x4, l2);  // ht = 2*pg
        bf16x4 vhi = __builtin_bit_cast(bf16x4, h2);  // ht = 2*pg+1
#pragma unroll
        for (int qs = 0; qs < 2; ++qs) {
          u32x2 pd = {d[qs][t][0], d[qs][t][1]};
          bf16x4 pb = __builtin_bit_cast(bf16x4, pd);
          o[qs][2 * pg]     = MFMA16(vlo, pb, o[qs][2 * pg]);
          o[qs][2 * pg + 1] = MFMA16(vhi, pb, o[qs][2 * pg + 1]);
        }
      }
#else
    // ---- fallback: shfl-transpose P (K=32) + shfl-gather V bf16x8 ----
    bf16x8 pbf[2];
#pragma unroll
    for (int qs = 0; qs < 2; ++qs) {
      unsigned dA0 = d[qs][0][0], dB0 = d[qs][0][1];
      unsigned dA1 = d[qs][1][0], dB1 = d[qs][1][1];
      int base = ((quad & 1) << 5) + col;
      unsigned a0  = __shfl(dA0, base),      a1  = __shfl(dA1, base);
      unsigned b0  = __shfl(dB0, base),      b1  = __shfl(dB1, base);
      unsigned a0h = __shfl(dA0, base + 16), a1h = __shfl(dA1, base + 16);
      unsigned b0h = __shfl(dB0, base + 16), b1h = __shfl(dB1, base + 16);
      bool hi = quad >= 2;
      uint4 pu = make_uint4(hi ? a1 : a0, hi ? b1 : b0,
                            hi ? a1h : a0h, hi ? b1h : b0h);
      pbf[qs] = __builtin_bit_cast(bf16x8, pu);
    }
#pragma unroll
    for (int ht = 0; ht < 4; ++ht) {
      int pg = ht >> 1;
      bool odd = ht & 1;
      int L0 = ((quad & 1) * 2) * 16 + col, L1 = L0 + 16;
      uint4 u0 = __builtin_bit_cast(uint4, vv[pg]);
      uint4 u1 = __builtin_bit_cast(uint4, vv[2 + pg]);
      unsigned s0 = odd ? u0.z : u0.x, s1 = odd ? u0.w : u0.y;
      unsigned s2 = odd ? u1.z : u1.x, s3 = odd ? u1.w : u1.y;
      unsigned d0a = __shfl(s0, L0), d1a = __shfl(s1, L0);
      unsigned d2a = __shfl(s0, L1), d3a = __shfl(s1, L1);
      unsigned d0b = __shfl(s2, L0), d1b = __shfl(s3, L0);
      unsigned d2b = __shfl(s2, L1), d3b = __shfl(s3, L1);
      bool t1 = quad >= 2;
      uint4 vu = make_uint4(t1 ? d0b : d0a, t1 ? d1b : d1a,
                            t1 ? d2b : d2a, t1 ? d3b : d3a);
      bf16x8 vf8 = __builtin_bit_cast(bf16x8, vu);
#pragma unroll
      for (int qs = 0; qs < 2; ++qs)
        o[qs][ht] = MFMA_BF16(vf8, pbf[qs], o[qs][ht]);
    }
#endif
  }

  // ---- 4-way split-K combine (pure fp32 add; no-max softmax) ----
  __syncthreads();
  float* comb = (float*)lds;  // overlays K staging
  if (wave > 0) {
    float* p = comb + ((wave - 1) * 64 + lane) * 36;
#pragma unroll
    for (int qs = 0; qs < 2; ++qs)
#pragma unroll
      for (int ht = 0; ht < 4; ++ht)
        *(f32x4*)(p + (qs * 4 + ht) * 4) = o[qs][ht];
    p[32] = osum[0];
    p[33] = osum[1];
  }
  __syncthreads();
  if (wave == 0) {
#pragma unroll
    for (int w = 1; w < 4; ++w) {
      const float* p = comb + ((w - 1) * 64 + lane) * 36;
#pragma unroll
      for (int qs = 0; qs < 2; ++qs)
#pragma unroll
        for (int ht = 0; ht < 4; ++ht)
          o[qs][ht] += *(const f32x4*)(p + (qs * 4 + ht) * 4);
      osum[0] += p[32];
      osum[1] += p[33];
    }
    // ---- epilogue: O^T C-layout -> packed float4 stores ----
#pragma unroll
    for (int qs = 0; qs < 2; ++qs) {
      float inv = 1.0f / osum[qs];
#pragma unroll
      for (int ht = 0; ht < 4; ++ht) {
        f32x4 val = o[qs][ht];
#pragma unroll
        for (int rr = 0; rr < 4; ++rr) val[rr] *= inv;
        *(f32x4*)(out + (qbase + qs * 16 + col) * 64 + ht * 16 + quad * 4) = val;
      }
    }
  }
}

// ---------------------------------------------------------------------------
extern "C" void kernel_launch(void* const* d_in, const int* in_sizes, int n_in,
                              void* d_out, int out_size, void* d_ws, size_t ws_size,
                              hipStream_t stream) {
  const float* x  = (const float*)d_in[0];
  const float* Wk = (const float*)d_in[1];
  const float* Wq = (const float*)d_in[2];
  const float* Wv = (const float*)d_in[3];
  float* out = (float*)d_out;

  char* ws = (char*)d_ws;
  // ws layout: wtf (294912 B) | qb 2MB | kb 2MB | vfb 2MB
  short* wtf = (short*)(ws);
  short* qb  = (short*)(ws + (512 << 10));
  short* kb  = (short*)(ws + (512 << 10) + (2 << 20));
  short* vfb = (short*)(ws + (512 << 10) + (4 << 20));

  prep_wt<<<72, 256, 0, stream>>>(Wk, Wq, Wv, wtf);
  proj_kernel<<<512, 256, 0, stream>>>(x, wtf, qb, kb, vfb);
  attn_kernel<<<512, 256, 0, stream>>>(qb, kb, vfb, out);
}